// Round 2
// baseline (784.326 us; speedup 1.0000x reference)
//
#include <hip/hip_runtime.h>
#include <hip/hip_bf16.h>

// Fused Swin window attention for MI355X (gfx950) — round 2.
// One block per 8x8 window (2048 blocks x 256 threads, 4 waves).
// Changes vs r1 (which was occupancy-bound: 138KB LDS -> 1 block/CU, Occ 11.6%):
//   * x is never staged in LDS: QKV A-frags load fp32 from global (L2-hot) + cvt.
//   * q round-trips through the k LDS region once, then lives in 32 VGPRs/wave.
//   * p/oh use per-wave scratch (wave-local, no barriers).
//   * LDS = k(64x264) + vT(256x72) + 4x(16x72) = 79,872 B -> 2 blocks/CU.
//   * weights pre-tiled in prep to MFMA fragment order -> B-frag loads are
//     lane-contiguous 1KB coalesced reads from L2.

typedef __attribute__((ext_vector_type(8))) short bf16x8;
typedef __attribute__((ext_vector_type(4))) float f32x4;

__device__ __forceinline__ f32x4 mfma16(bf16x8 a, bf16x8 b, f32x4 c) {
  return __builtin_amdgcn_mfma_f32_16x16x32_bf16(a, b, c, 0, 0, 0);
}

__device__ __forceinline__ unsigned short f2bf(float f) {
  union { float f; unsigned u; } v; v.f = f;
  unsigned r = v.u + 0x7fffu + ((v.u >> 16) & 1u);
  return (unsigned short)(r >> 16);
}

__device__ __forceinline__ bf16x8 cvt8(const float* p) {
  const float4 a = *(const float4*)p;
  const float4 b = *(const float4*)(p + 4);
  bf16x8 r;
  r[0] = (short)f2bf(a.x); r[1] = (short)f2bf(a.y);
  r[2] = (short)f2bf(a.z); r[3] = (short)f2bf(a.w);
  r[4] = (short)f2bf(b.x); r[5] = (short)f2bf(b.y);
  r[6] = (short)f2bf(b.z); r[7] = (short)f2bf(b.w);
  return r;
}

#define SCALE 0.17677669529663687f

// LDS layout (ushort elements)
#define QKSTR 264              // q/k region row stride (64 rows)
#define VSTR  72               // vT region row stride (256 rows)
#define SSTR  72               // per-wave scratch row stride (16 rows)
#define OFF_QK 0
#define OFF_VT 16896           // 64*264
#define OFF_SC 35328           // + 256*72
#define SMEM_ELTS 39936        // + 4*16*72  => 79,872 bytes -> 2 blocks/CU

// Weight tiled layout: elem(n,k) -> ((((n>>4)*8 + (k>>5))*4 + ((k>>3)&3))*16 + (n&15))*8 + (k&7)
// so a B-fragment (n-tile, kk) load is 64 lanes x 16B contiguous.
__global__ void prep_kernel(const float* __restrict__ w_qkv,
                            const float* __restrict__ w_out,
                            const float* __restrict__ pos_emb,
                            unsigned short* __restrict__ wqkvT,
                            unsigned short* __restrict__ woutT,
                            float* __restrict__ bias64) {
  const int stride = gridDim.x * blockDim.x;
  const int tid = blockIdx.x * blockDim.x + threadIdx.x;
  for (int i = tid; i < 768 * 256; i += stride) {
    int n = i >> 8, k = i & 255;
    int off = ((((n >> 4) * 8 + (k >> 5)) * 4 + ((k >> 3) & 3)) * 16 + (n & 15)) * 8 + (k & 7);
    wqkvT[off] = f2bf(w_qkv[k * 768 + n]);
  }
  for (int i = tid; i < 256 * 256; i += stride) {
    int n = i >> 8, k = i & 255;
    int off = ((((n >> 4) * 8 + (k >> 5)) * 4 + ((k >> 3) & 3)) * 16 + (n & 15)) * 8 + (k & 7);
    woutT[off] = f2bf(w_out[k * 256 + n]);
  }
  for (int i = tid; i < 64 * 64; i += stride) {
    int a = i >> 6, b = i & 63;
    int d0 = (b >> 3) - (a >> 3) + 7;
    int d1 = (b & 7) - (a & 7) + 7;
    bias64[i] = pos_emb[d0 * 15 + d1];
  }
}

#define QKV_MFMA(acc_, col0_)                                                   \
  _Pragma("unroll")                                                             \
  for (int kk = 0; kk < 8; ++kk) {                                              \
    bf16x8 a_[4];                                                               \
    _Pragma("unroll")                                                           \
    for (int rt = 0; rt < 4; ++rt) a_[rt] = cvt8(rowp[rt] + kk * 32 + lq * 8);  \
    bf16x8 b_[4];                                                               \
    _Pragma("unroll")                                                           \
    for (int ct = 0; ct < 4; ++ct)                                              \
      b_[ct] = *(const bf16x8*)&wqkvT[(((((col0_) >> 4) + ct) * 8 + kk) * 4 + lq) * 128 + l15 * 8]; \
    _Pragma("unroll")                                                           \
    for (int rt = 0; rt < 4; ++rt)                                              \
      _Pragma("unroll")                                                         \
      for (int ct = 0; ct < 4; ++ct)                                            \
        acc_[rt][ct] = mfma16(a_[rt], b_[ct], acc_[rt][ct]);                    \
  }

__global__ __launch_bounds__(256, 2)
void winattn_kernel(const float* __restrict__ x,
                    const unsigned short* __restrict__ wqkvT,
                    const unsigned short* __restrict__ woutT,
                    const float* __restrict__ bias64,
                    const float* __restrict__ b_out,
                    float* __restrict__ out) {
  __shared__ unsigned short smem[SMEM_ELTS];

  const int tid = threadIdx.x;
  const int lane = tid & 63;
  const int w = tid >> 6;
  const int l15 = lane & 15;
  const int lq = lane >> 4;

  const int bid = blockIdx.x;
  const int win = bid & 255;
  const int img = bid >> 8;
  const int wy = win >> 4, wx = win & 15;

  unsigned short* qk_lds = smem + OFF_QK;
  unsigned short* vT_lds = smem + OFF_VT;
  unsigned short* sc = smem + OFF_SC + w * (16 * SSTR);   // wave-local scratch

  const f32x4 zero4 = {0.f, 0.f, 0.f, 0.f};
  const size_t img_base = (size_t)img * 128 * 128 * 256;

  // per-lane x row pointers (pixel = rt*16 + l15)
  const float* rowp[4];
#pragma unroll
  for (int rt = 0; rt < 4; ++rt) {
    int p = rt * 16 + l15;
    rowp[rt] = x + img_base +
        ((size_t)((wy * 8 + (p >> 3)) * 128 + wx * 8 + (p & 7))) * 256;
  }

  // ---------- Q chunk: cols [w*64, w*64+64) of q ----------
  {
    const int col0 = w * 64;
    f32x4 acc[4][4];
#pragma unroll
    for (int rt = 0; rt < 4; ++rt)
#pragma unroll
      for (int ct = 0; ct < 4; ++ct) acc[rt][ct] = zero4;
    QKV_MFMA(acc, col0)
#pragma unroll
    for (int rt = 0; rt < 4; ++rt)
#pragma unroll
      for (int ct = 0; ct < 4; ++ct)
#pragma unroll
        for (int r = 0; r < 4; ++r)
          qk_lds[(rt * 16 + lq * 4 + r) * QKSTR + col0 + ct * 16 + l15] =
              f2bf(acc[rt][ct][r]);
  }
  __syncthreads();

  // ---------- pull q A-frags into registers (wave rows w*16..+16) ----------
  bf16x8 qf[8];
#pragma unroll
  for (int h = 0; h < 8; ++h)
    qf[h] = *(const bf16x8*)&qk_lds[(w * 16 + l15) * QKSTR + h * 32 + lq * 8];

  float bias_r[4][4];
#pragma unroll
  for (int ct = 0; ct < 4; ++ct)
#pragma unroll
    for (int r = 0; r < 4; ++r)
      bias_r[ct][r] = bias64[(w * 16 + lq * 4 + r) * 64 + ct * 16 + l15];

  // ---------- K chunk: cols [256 + w*64, +64) ----------
  {
    const int col0 = 256 + w * 64;
    f32x4 acc[4][4];
#pragma unroll
    for (int rt = 0; rt < 4; ++rt)
#pragma unroll
      for (int ct = 0; ct < 4; ++ct) acc[rt][ct] = zero4;
    QKV_MFMA(acc, col0)
    __syncthreads();   // all q-frag reads done; safe to overwrite qk region
#pragma unroll
    for (int rt = 0; rt < 4; ++rt)
#pragma unroll
      for (int ct = 0; ct < 4; ++ct)
#pragma unroll
        for (int r = 0; r < 4; ++r)
          qk_lds[(rt * 16 + lq * 4 + r) * QKSTR + (col0 - 256) + ct * 16 + l15] =
              f2bf(acc[rt][ct][r]);
  }

  // ---------- V chunk: cols [512 + w*64, +64), scatter transposed ----------
  {
    const int col0 = 512 + w * 64;
    f32x4 acc[4][4];
#pragma unroll
    for (int rt = 0; rt < 4; ++rt)
#pragma unroll
      for (int ct = 0; ct < 4; ++ct) acc[rt][ct] = zero4;
    QKV_MFMA(acc, col0)
#pragma unroll
    for (int rt = 0; rt < 4; ++rt)
#pragma unroll
      for (int ct = 0; ct < 4; ++ct)
#pragma unroll
        for (int r = 0; r < 4; ++r)
          vT_lds[((col0 - 512) + ct * 16 + l15) * VSTR + rt * 16 + lq * 4 + r] =
              f2bf(acc[rt][ct][r]);
  }
  __syncthreads();

  // ---------- attention + fused out-proj (wave owns rows w*16..+16) ----------
  f32x4 ACC[16];
#pragma unroll
  for (int ct = 0; ct < 16; ++ct) ACC[ct] = zero4;

  for (int h = 0; h < 8; ++h) {
    // S = q k^T (K=32, one k-step)
    f32x4 s[4];
#pragma unroll
    for (int ct = 0; ct < 4; ++ct) {
      const bf16x8 bk = *(const bf16x8*)&qk_lds[(ct * 16 + l15) * QKSTR + h * 32 + lq * 8];
      s[ct] = mfma16(qf[h], bk, zero4);
    }
#pragma unroll
    for (int ct = 0; ct < 4; ++ct)
#pragma unroll
      for (int r = 0; r < 4; ++r)
        s[ct][r] = s[ct][r] * SCALE + bias_r[ct][r];

    // row softmax (row spread over 16 lanes of a quarter)
    float rsum[4];
#pragma unroll
    for (int r = 0; r < 4; ++r) {
      float mx = fmaxf(fmaxf(s[0][r], s[1][r]), fmaxf(s[2][r], s[3][r]));
      mx = fmaxf(mx, __shfl_xor(mx, 1));
      mx = fmaxf(mx, __shfl_xor(mx, 2));
      mx = fmaxf(mx, __shfl_xor(mx, 4));
      mx = fmaxf(mx, __shfl_xor(mx, 8));
      float sm = 0.f;
#pragma unroll
      for (int ct = 0; ct < 4; ++ct) {
        float e = __expf(s[ct][r] - mx);
        s[ct][r] = e;
        sm += e;
      }
      sm += __shfl_xor(sm, 1);
      sm += __shfl_xor(sm, 2);
      sm += __shfl_xor(sm, 4);
      sm += __shfl_xor(sm, 8);
      rsum[r] = 1.0f / sm;
    }

    // P -> wave-local scratch (rows 0..15 local)
#pragma unroll
    for (int ct = 0; ct < 4; ++ct)
#pragma unroll
      for (int r = 0; r < 4; ++r)
        sc[(lq * 4 + r) * SSTR + ct * 16 + l15] = f2bf(s[ct][r]);

    // PV (16x32, K=64)
    f32x4 o[2];
    o[0] = zero4; o[1] = zero4;
#pragma unroll
    for (int kk = 0; kk < 2; ++kk) {
      const bf16x8 ap = *(const bf16x8*)&sc[l15 * SSTR + kk * 32 + lq * 8];
#pragma unroll
      for (int ct = 0; ct < 2; ++ct) {
        const bf16x8 bv = *(const bf16x8*)&vT_lds[(h * 32 + ct * 16 + l15) * VSTR + kk * 32 + lq * 8];
        o[ct] = mfma16(ap, bv, o[ct]);
      }
    }
    // normalize, stash oh in scratch (aliases p: p fully consumed)
#pragma unroll
    for (int ct = 0; ct < 2; ++ct)
#pragma unroll
      for (int r = 0; r < 4; ++r)
        sc[(lq * 4 + r) * SSTR + ct * 16 + l15] = f2bf(o[ct][r] * rsum[r]);

    // out-proj slice: ACC(16x256) += oh(16x32) @ w_out[h*32.., :]
    const bf16x8 ao = *(const bf16x8*)&sc[l15 * SSTR + lq * 8];
#pragma unroll
    for (int ct = 0; ct < 16; ++ct) {
      const bf16x8 bw = *(const bf16x8*)&woutT[((ct * 8 + h) * 4 + lq) * 128 + l15 * 8];
      ACC[ct] = mfma16(ao, bw, ACC[ct]);
    }
  }

  // ---------- epilogue ----------
  {
#pragma unroll
    for (int ct = 0; ct < 16; ++ct) {
      const int n = ct * 16 + l15;
      const float bo = b_out[n];
#pragma unroll
      for (int r = 0; r < 4; ++r) {
        const int p = w * 16 + lq * 4 + r;
        const size_t off = img_base +
            (((size_t)(wy * 8 + (p >> 3)) * 128) + (wx * 8 + (p & 7))) * 256 + n;
        out[off] = ACC[ct][r] + bo;
      }
    }
  }
}

extern "C" void kernel_launch(void* const* d_in, const int* in_sizes, int n_in,
                              void* d_out, int out_size, void* d_ws, size_t ws_size,
                              hipStream_t stream) {
  const float* x       = (const float*)d_in[0];
  const float* w_qkv   = (const float*)d_in[1];
  const float* pos_emb = (const float*)d_in[2];
  const float* w_out   = (const float*)d_in[3];
  const float* b_out   = (const float*)d_in[4];
  float* out = (float*)d_out;

  unsigned short* wqkvT = (unsigned short*)d_ws;
  unsigned short* woutT = wqkvT + 768 * 256;
  float* bias64 = (float*)(woutT + 256 * 256);

  prep_kernel<<<96, 256, 0, stream>>>(w_qkv, w_out, pos_emb, wqkvT, woutT, bias64);
  winattn_kernel<<<2048, 256, 0, stream>>>(x, wqkvT, woutT, bias64, b_out, out);
}

// Round 3
// 352.796 us; speedup vs baseline: 2.2232x; 2.2232x over previous
//
#include <hip/hip_runtime.h>
#include <hip/hip_bf16.h>

// Fused Swin window attention for MI355X (gfx950) — round 3.
// One block per 8x8 window (2048 blocks x 256 threads, 4 waves).
// r1: coalesced LDS staging, but 138KB LDS -> 1 block/CU (latency-bound, 340us).
// r2: global x gathers -> 6x HBM traffic explosion (784us). REVERTED.
// r3 = r1's memory structure + r2's occupancy:
//   * x staged once to LDS region A (coalesced float4 -> bf16).
//   * q computed first, round-trips via region B, then held as A-frags in VGPRs.
//   * k,v accumulate in registers (128 VGPR peak), then k -> region B (over q),
//     vT -> region A (over dead x). LDS total 79,872 B -> 2 blocks/CU.
//   * weights pre-tiled to MFMA fragment order (lane-contiguous 1KB L2 reads).

typedef __attribute__((ext_vector_type(8))) short bf16x8;
typedef __attribute__((ext_vector_type(4))) float f32x4;

__device__ __forceinline__ f32x4 mfma16(bf16x8 a, bf16x8 b, f32x4 c) {
  return __builtin_amdgcn_mfma_f32_16x16x32_bf16(a, b, c, 0, 0, 0);
}

__device__ __forceinline__ unsigned short f2bf(float f) {
  union { float f; unsigned u; } v; v.f = f;
  unsigned r = v.u + 0x7fffu + ((v.u >> 16) & 1u);
  return (unsigned short)(r >> 16);
}

#define SCALE 0.17677669529663687f

// LDS layout (ushort elements)
#define XSTR 264     // x / q / k row stride (64 rows)
#define VSTR 72      // vT row stride (256 rows)
#define SSTR 72      // per-wave scratch row stride (16 rows)
#define OFF_A  0     // region A: x (64x264=16896) then vT (256x72=18432)
#define OFF_B  18432 // region B: q then k (64x264=16896)
#define OFF_SC 35328 // scratch: 4 waves x 16 x 72 = 4608
#define SMEM_ELTS 39936  // 79,872 bytes -> 2 blocks/CU

// Weight tiled layout: elem(n,k) -> ((((n>>4)*8+(k>>5))*4+((k>>3)&3))*16+(n&15))*8+(k&7)
__global__ void prep_kernel(const float* __restrict__ w_qkv,
                            const float* __restrict__ w_out,
                            const float* __restrict__ pos_emb,
                            unsigned short* __restrict__ wqkvT,
                            unsigned short* __restrict__ woutT,
                            float* __restrict__ bias64) {
  const int stride = gridDim.x * blockDim.x;
  const int tid = blockIdx.x * blockDim.x + threadIdx.x;
  for (int i = tid; i < 768 * 256; i += stride) {
    int n = i >> 8, k = i & 255;
    int off = ((((n >> 4) * 8 + (k >> 5)) * 4 + ((k >> 3) & 3)) * 16 + (n & 15)) * 8 + (k & 7);
    wqkvT[off] = f2bf(w_qkv[k * 768 + n]);
  }
  for (int i = tid; i < 256 * 256; i += stride) {
    int n = i >> 8, k = i & 255;
    int off = ((((n >> 4) * 8 + (k >> 5)) * 4 + ((k >> 3) & 3)) * 16 + (n & 15)) * 8 + (k & 7);
    woutT[off] = f2bf(w_out[k * 256 + n]);
  }
  for (int i = tid; i < 64 * 64; i += stride) {
    int a = i >> 6, b = i & 63;
    int d0 = (b >> 3) - (a >> 3) + 7;
    int d1 = (b & 7) - (a & 7) + 7;
    bias64[i] = pos_emb[d0 * 15 + d1];
  }
}

// QKV GEMM step: A-frags from LDS x, B-frags from tiled weights (global/L2)
#define QKV_MFMA(acc_, col0_)                                                    \
  _Pragma("unroll")                                                              \
  for (int kk = 0; kk < 8; ++kk) {                                               \
    const int ko = kk * 32 + lq * 8;                                             \
    bf16x8 a_[4], b_[4];                                                         \
    _Pragma("unroll")                                                            \
    for (int rt = 0; rt < 4; ++rt)                                               \
      a_[rt] = *(const bf16x8*)&x_lds[(rt * 16 + l15) * XSTR + ko];              \
    _Pragma("unroll")                                                            \
    for (int ct = 0; ct < 4; ++ct)                                               \
      b_[ct] = *(const bf16x8*)&wqkvT[(((((col0_) >> 4) + ct) * 8 + kk) * 4 + lq) * 128 + l15 * 8]; \
    _Pragma("unroll")                                                            \
    for (int rt = 0; rt < 4; ++rt)                                               \
      _Pragma("unroll")                                                          \
      for (int ct = 0; ct < 4; ++ct)                                             \
        acc_[rt][ct] = mfma16(a_[rt], b_[ct], acc_[rt][ct]);                     \
  }

__global__ __launch_bounds__(256, 2)
void winattn_kernel(const float* __restrict__ x,
                    const unsigned short* __restrict__ wqkvT,
                    const unsigned short* __restrict__ woutT,
                    const float* __restrict__ bias64,
                    const float* __restrict__ b_out,
                    float* __restrict__ out) {
  __shared__ unsigned short smem[SMEM_ELTS];

  const int tid = threadIdx.x;
  const int lane = tid & 63;
  const int w = tid >> 6;
  const int l15 = lane & 15;
  const int lq = lane >> 4;

  const int bid = blockIdx.x;
  const int win = bid & 255;
  const int img = bid >> 8;
  const int wy = win >> 4, wx = win & 15;

  unsigned short* x_lds  = smem + OFF_A;   // x, later overwritten by vT
  unsigned short* vT_lds = smem + OFF_A;
  unsigned short* qk_lds = smem + OFF_B;   // q round-trip, then k
  unsigned short* sc = smem + OFF_SC + w * (16 * SSTR);

  const f32x4 zero4 = {0.f, 0.f, 0.f, 0.f};
  const size_t img_base = (size_t)img * 128 * 128 * 256;

  // ---------- phase 1: stage x window -> bf16 LDS (coalesced) ----------
  {
#pragma unroll
    for (int r = 0; r < 16; ++r) {
      int p = r * 4 + w;                 // pixel 0..63
      const float* src = x + img_base +
          (((size_t)(wy * 8 + (p >> 3)) * 128) + (wx * 8 + (p & 7))) * 256 + lane * 4;
      float4 v4 = *(const float4*)src;
      unsigned short* dst = &x_lds[p * XSTR + lane * 4];
      dst[0] = f2bf(v4.x); dst[1] = f2bf(v4.y);
      dst[2] = f2bf(v4.z); dst[3] = f2bf(v4.w);
    }
  }
  __syncthreads();   // bar1

  // ---------- phase 2a: Q chunk (cols w*64..+64), round-trip via B ----------
  {
    f32x4 acc[4][4];
#pragma unroll
    for (int rt = 0; rt < 4; ++rt)
#pragma unroll
      for (int ct = 0; ct < 4; ++ct) acc[rt][ct] = zero4;
    QKV_MFMA(acc, w * 64)
#pragma unroll
    for (int rt = 0; rt < 4; ++rt)
#pragma unroll
      for (int ct = 0; ct < 4; ++ct)
#pragma unroll
        for (int r = 0; r < 4; ++r)
          qk_lds[(rt * 16 + lq * 4 + r) * XSTR + w * 64 + ct * 16 + l15] =
              f2bf(acc[rt][ct][r]);
  }
  __syncthreads();   // bar2

  // q A-frags for this wave's 16 rows
  bf16x8 qf[8];
#pragma unroll
  for (int h = 0; h < 8; ++h)
    qf[h] = *(const bf16x8*)&qk_lds[(w * 16 + l15) * XSTR + h * 32 + lq * 8];

  float bias_r[4][4];
#pragma unroll
  for (int ct = 0; ct < 4; ++ct)
#pragma unroll
    for (int r = 0; r < 4; ++r)
      bias_r[ct][r] = bias64[(w * 16 + lq * 4 + r) * 64 + ct * 16 + l15];

  // ---------- phase 2b: K and V chunks accumulate in registers ----------
  f32x4 kacc[4][4], vacc[4][4];
#pragma unroll
  for (int rt = 0; rt < 4; ++rt)
#pragma unroll
    for (int ct = 0; ct < 4; ++ct) { kacc[rt][ct] = zero4; vacc[rt][ct] = zero4; }
  QKV_MFMA(kacc, 256 + w * 64)
  QKV_MFMA(vacc, 512 + w * 64)
  __syncthreads();   // bar3: all qf reads (B) and all x reads (A) complete

  // k -> region B (over q); vT -> region A (over x)
#pragma unroll
  for (int rt = 0; rt < 4; ++rt)
#pragma unroll
    for (int ct = 0; ct < 4; ++ct)
#pragma unroll
      for (int r = 0; r < 4; ++r) {
        qk_lds[(rt * 16 + lq * 4 + r) * XSTR + w * 64 + ct * 16 + l15] =
            f2bf(kacc[rt][ct][r]);
        vT_lds[(w * 64 + ct * 16 + l15) * VSTR + rt * 16 + lq * 4 + r] =
            f2bf(vacc[rt][ct][r]);
      }
  __syncthreads();   // bar4

  // ---------- phase 3: attention + fused out-proj (wave rows w*16..+16) ----------
  f32x4 ACC[16];
#pragma unroll
  for (int ct = 0; ct < 16; ++ct) ACC[ct] = zero4;

  for (int h = 0; h < 8; ++h) {
    // S = q k^T (K=32, one k-step)
    f32x4 s[4];
#pragma unroll
    for (int ct = 0; ct < 4; ++ct) {
      const bf16x8 bk = *(const bf16x8*)&qk_lds[(ct * 16 + l15) * XSTR + h * 32 + lq * 8];
      s[ct] = mfma16(qf[h], bk, zero4);
    }
#pragma unroll
    for (int ct = 0; ct < 4; ++ct)
#pragma unroll
      for (int r = 0; r < 4; ++r)
        s[ct][r] = s[ct][r] * SCALE + bias_r[ct][r];

    // row softmax (row spread over 16 lanes of a quarter)
    float rsum[4];
#pragma unroll
    for (int r = 0; r < 4; ++r) {
      float mx = fmaxf(fmaxf(s[0][r], s[1][r]), fmaxf(s[2][r], s[3][r]));
      mx = fmaxf(mx, __shfl_xor(mx, 1));
      mx = fmaxf(mx, __shfl_xor(mx, 2));
      mx = fmaxf(mx, __shfl_xor(mx, 4));
      mx = fmaxf(mx, __shfl_xor(mx, 8));
      float sm = 0.f;
#pragma unroll
      for (int ct = 0; ct < 4; ++ct) {
        float e = __expf(s[ct][r] - mx);
        s[ct][r] = e;
        sm += e;
      }
      sm += __shfl_xor(sm, 1);
      sm += __shfl_xor(sm, 2);
      sm += __shfl_xor(sm, 4);
      sm += __shfl_xor(sm, 8);
      rsum[r] = 1.0f / sm;
    }

    // P -> wave-local scratch
#pragma unroll
    for (int ct = 0; ct < 4; ++ct)
#pragma unroll
      for (int r = 0; r < 4; ++r)
        sc[(lq * 4 + r) * SSTR + ct * 16 + l15] = f2bf(s[ct][r]);

    // PV (16x32, K=64)
    f32x4 o[2];
    o[0] = zero4; o[1] = zero4;
#pragma unroll
    for (int kk = 0; kk < 2; ++kk) {
      const bf16x8 ap = *(const bf16x8*)&sc[l15 * SSTR + kk * 32 + lq * 8];
#pragma unroll
      for (int ct = 0; ct < 2; ++ct) {
        const bf16x8 bv = *(const bf16x8*)&vT_lds[(h * 32 + ct * 16 + l15) * VSTR + kk * 32 + lq * 8];
        o[ct] = mfma16(ap, bv, o[ct]);
      }
    }
    // normalize, stash oh (aliases p: p fully consumed)
#pragma unroll
    for (int ct = 0; ct < 2; ++ct)
#pragma unroll
      for (int r = 0; r < 4; ++r)
        sc[(lq * 4 + r) * SSTR + ct * 16 + l15] = f2bf(o[ct][r] * rsum[r]);

    // out-proj slice: ACC(16x256) += oh(16x32) @ w_out[h*32.., :]
    const bf16x8 ao = *(const bf16x8*)&sc[l15 * SSTR + lq * 8];
#pragma unroll
    for (int ct = 0; ct < 16; ++ct) {
      const bf16x8 bw = *(const bf16x8*)&woutT[((ct * 8 + h) * 4 + lq) * 128 + l15 * 8];
      ACC[ct] = mfma16(ao, bw, ACC[ct]);
    }
  }

  // ---------- phase 4: epilogue ----------
  {
#pragma unroll
    for (int ct = 0; ct < 16; ++ct) {
      const int n = ct * 16 + l15;
      const float bo = b_out[n];
#pragma unroll
      for (int r = 0; r < 4; ++r) {
        const int p = w * 16 + lq * 4 + r;
        const size_t off = img_base +
            (((size_t)(wy * 8 + (p >> 3)) * 128) + (wx * 8 + (p & 7))) * 256 + n;
        out[off] = ACC[ct][r] + bo;
      }
    }
  }
}

extern "C" void kernel_launch(void* const* d_in, const int* in_sizes, int n_in,
                              void* d_out, int out_size, void* d_ws, size_t ws_size,
                              hipStream_t stream) {
  const float* x       = (const float*)d_in[0];
  const float* w_qkv   = (const float*)d_in[1];
  const float* pos_emb = (const float*)d_in[2];
  const float* w_out   = (const float*)d_in[3];
  const float* b_out   = (const float*)d_in[4];
  float* out = (float*)d_out;

  unsigned short* wqkvT = (unsigned short*)d_ws;
  unsigned short* woutT = wqkvT + 768 * 256;
  float* bias64 = (float*)(woutT + 256 * 256);

  prep_kernel<<<96, 256, 0, stream>>>(w_qkv, w_out, pos_emb, wqkvT, woutT, bias64);
  winattn_kernel<<<2048, 256, 0, stream>>>(x, wqkvT, woutT, bias64, b_out, out);
}

// Round 4
// 183.925 us; speedup vs baseline: 4.2644x; 1.9181x over previous
//
#include <hip/hip_runtime.h>
#include <hip/hip_bf16.h>

// Fused Swin window attention for MI355X (gfx950) — round 4.
// One block per 8x8 window (2048 blocks x 256 threads, 4 waves), 2 blocks/CU.
// r3 lessons (352us, no pipe >30%):
//   * kacc+vacc simultaneously live = 128 regs -> spills (WRITE_SIZE +113MB).
//     FIX: serialize K chunk (compute, barrier, store) before V chunk.
//   * softmax used 256 serial ds_bpermute (__shfl_xor) per wave.
//     FIX: drop max-subtract (|s| <~ 6, exp fp32-safe) and compute row sums
//     on the MATRIX pipe: mfma(P_frag, ones) yields row sums in C-frag layout.
//   * manual 3-op RNE f2bf -> __float2bfloat16 (compiler packed cvt).
//   * exp via v_exp_f32 (exp2) directly: bias & scale pre-multiplied by log2e.

typedef __attribute__((ext_vector_type(8))) short bf16x8;
typedef __attribute__((ext_vector_type(4))) float f32x4;

__device__ __forceinline__ f32x4 mfma16(bf16x8 a, bf16x8 b, f32x4 c) {
  return __builtin_amdgcn_mfma_f32_16x16x32_bf16(a, b, c, 0, 0, 0);
}

__device__ __forceinline__ unsigned short f2bf(float f) {
  __hip_bfloat16 h = __float2bfloat16(f);
  return *reinterpret_cast<unsigned short*>(&h);
}

#define LOG2E 1.4426950408889634f
#define EXPSCALE (0.17677669529663687f * 1.4426950408889634f)

// LDS layout (ushort elements)
#define XSTR 264     // x / q / k row stride (64 rows)
#define VSTR 72      // vT row stride (256 rows)
#define SSTR 72      // per-wave scratch row stride (16 rows)
#define OFF_A  0     // region A: x (64x264=16896) then vT (256x72=18432)
#define OFF_B  18432 // region B: q then k (64x264=16896)
#define OFF_SC 35328 // scratch: 4 waves x 16 x 72 = 4608
#define SMEM_ELTS 39936  // 79,872 bytes -> 2 blocks/CU

// Weight tiled layout: elem(n,k) -> ((((n>>4)*8+(k>>5))*4+((k>>3)&3))*16+(n&15))*8+(k&7)
__global__ void prep_kernel(const float* __restrict__ w_qkv,
                            const float* __restrict__ w_out,
                            const float* __restrict__ pos_emb,
                            unsigned short* __restrict__ wqkvT,
                            unsigned short* __restrict__ woutT,
                            float* __restrict__ bias64) {
  const int stride = gridDim.x * blockDim.x;
  const int tid = blockIdx.x * blockDim.x + threadIdx.x;
  for (int i = tid; i < 768 * 256; i += stride) {
    int n = i >> 8, k = i & 255;
    int off = ((((n >> 4) * 8 + (k >> 5)) * 4 + ((k >> 3) & 3)) * 16 + (n & 15)) * 8 + (k & 7);
    wqkvT[off] = f2bf(w_qkv[k * 768 + n]);
  }
  for (int i = tid; i < 256 * 256; i += stride) {
    int n = i >> 8, k = i & 255;
    int off = ((((n >> 4) * 8 + (k >> 5)) * 4 + ((k >> 3) & 3)) * 16 + (n & 15)) * 8 + (k & 7);
    woutT[off] = f2bf(w_out[k * 256 + n]);
  }
  for (int i = tid; i < 64 * 64; i += stride) {
    int a = i >> 6, b = i & 63;
    int d0 = (b >> 3) - (a >> 3) + 7;
    int d1 = (b & 7) - (a & 7) + 7;
    bias64[i] = pos_emb[d0 * 15 + d1] * LOG2E;   // pre-scaled for exp2
  }
}

// QKV GEMM step: A-frags from LDS x, B-frags from tiled weights (global/L2)
#define QKV_MFMA(acc_, col0_)                                                    \
  _Pragma("unroll")                                                              \
  for (int kk = 0; kk < 8; ++kk) {                                               \
    const int ko = kk * 32 + lq * 8;                                             \
    bf16x8 a_[4], b_[4];                                                         \
    _Pragma("unroll")                                                            \
    for (int rt = 0; rt < 4; ++rt)                                               \
      a_[rt] = *(const bf16x8*)&x_lds[(rt * 16 + l15) * XSTR + ko];              \
    _Pragma("unroll")                                                            \
    for (int ct = 0; ct < 4; ++ct)                                               \
      b_[ct] = *(const bf16x8*)&wqkvT[(((((col0_) >> 4) + ct) * 8 + kk) * 4 + lq) * 128 + l15 * 8]; \
    _Pragma("unroll")                                                            \
    for (int rt = 0; rt < 4; ++rt)                                               \
      _Pragma("unroll")                                                          \
      for (int ct = 0; ct < 4; ++ct)                                             \
        acc_[rt][ct] = mfma16(a_[rt], b_[ct], acc_[rt][ct]);                     \
  }

__global__ __launch_bounds__(256, 2)
void winattn_kernel(const float* __restrict__ x,
                    const unsigned short* __restrict__ wqkvT,
                    const unsigned short* __restrict__ woutT,
                    const float* __restrict__ bias64,
                    const float* __restrict__ b_out,
                    float* __restrict__ out) {
  __shared__ unsigned short smem[SMEM_ELTS];

  const int tid = threadIdx.x;
  const int lane = tid & 63;
  const int w = tid >> 6;
  const int l15 = lane & 15;
  const int lq = lane >> 4;

  const int bid = blockIdx.x;
  const int win = bid & 255;
  const int img = bid >> 8;
  const int wy = win >> 4, wx = win & 15;

  unsigned short* x_lds  = smem + OFF_A;   // x, later overwritten by vT
  unsigned short* vT_lds = smem + OFF_A;
  unsigned short* qk_lds = smem + OFF_B;   // q round-trip, then k
  unsigned short* sc = smem + OFF_SC + w * (16 * SSTR);

  const f32x4 zero4 = {0.f, 0.f, 0.f, 0.f};
  const size_t img_base = (size_t)img * 128 * 128 * 256;

  // bias (pre-scaled by log2e) — load early, L2-hot
  float bias_r[4][4];
#pragma unroll
  for (int ct = 0; ct < 4; ++ct)
#pragma unroll
    for (int r = 0; r < 4; ++r)
      bias_r[ct][r] = bias64[(w * 16 + lq * 4 + r) * 64 + ct * 16 + l15];

  // ---------- phase 1: stage x window -> bf16 LDS (coalesced) ----------
  {
#pragma unroll
    for (int r = 0; r < 16; ++r) {
      int p = r * 4 + w;                 // pixel 0..63
      const float* src = x + img_base +
          (((size_t)(wy * 8 + (p >> 3)) * 128) + (wx * 8 + (p & 7))) * 256 + lane * 4;
      float4 v4 = *(const float4*)src;
      union { unsigned short u[4]; uint2 v; } pk;
      pk.u[0] = f2bf(v4.x); pk.u[1] = f2bf(v4.y);
      pk.u[2] = f2bf(v4.z); pk.u[3] = f2bf(v4.w);
      *(uint2*)&x_lds[p * XSTR + lane * 4] = pk.v;   // single b64 write
    }
  }
  __syncthreads();   // bar1

  // ---------- phase 2a: Q chunk (cols w*64..+64), round-trip via B ----------
  {
    f32x4 acc[4][4];
#pragma unroll
    for (int rt = 0; rt < 4; ++rt)
#pragma unroll
      for (int ct = 0; ct < 4; ++ct) acc[rt][ct] = zero4;
    QKV_MFMA(acc, w * 64)
#pragma unroll
    for (int rt = 0; rt < 4; ++rt)
#pragma unroll
      for (int ct = 0; ct < 4; ++ct)
#pragma unroll
        for (int r = 0; r < 4; ++r)
          qk_lds[(rt * 16 + lq * 4 + r) * XSTR + w * 64 + ct * 16 + l15] =
              f2bf(acc[rt][ct][r]);
  }
  __syncthreads();   // bar2

  // q A-frags for this wave's 16 rows
  bf16x8 qf[8];
#pragma unroll
  for (int h = 0; h < 8; ++h)
    qf[h] = *(const bf16x8*)&qk_lds[(w * 16 + l15) * XSTR + h * 32 + lq * 8];

  // ---------- phase 2b: K chunk (registers -> barrier -> LDS) ----------
  {
    f32x4 kacc[4][4];
#pragma unroll
    for (int rt = 0; rt < 4; ++rt)
#pragma unroll
      for (int ct = 0; ct < 4; ++ct) kacc[rt][ct] = zero4;
    QKV_MFMA(kacc, 256 + w * 64)
    __syncthreads();   // bar3: all qf reads done -> safe to overwrite B
#pragma unroll
    for (int rt = 0; rt < 4; ++rt)
#pragma unroll
      for (int ct = 0; ct < 4; ++ct)
#pragma unroll
        for (int r = 0; r < 4; ++r)
          qk_lds[(rt * 16 + lq * 4 + r) * XSTR + w * 64 + ct * 16 + l15] =
              f2bf(kacc[rt][ct][r]);
  }

  // ---------- phase 2c: V chunk (registers -> barrier -> LDS, transposed) ----------
  {
    f32x4 vacc[4][4];
#pragma unroll
    for (int rt = 0; rt < 4; ++rt)
#pragma unroll
      for (int ct = 0; ct < 4; ++ct) vacc[rt][ct] = zero4;
    QKV_MFMA(vacc, 512 + w * 64)
    __syncthreads();   // bar4: all x reads (region A) done -> safe to overwrite
#pragma unroll
    for (int rt = 0; rt < 4; ++rt)
#pragma unroll
      for (int ct = 0; ct < 4; ++ct)
#pragma unroll
        for (int r = 0; r < 4; ++r)
          vT_lds[(w * 64 + ct * 16 + l15) * VSTR + rt * 16 + lq * 4 + r] =
              f2bf(vacc[rt][ct][r]);
  }
  __syncthreads();   // bar5

  // ---------- phase 3: attention + fused out-proj (wave rows w*16..+16) ----------
  const short one_bf = (short)0x3F80;            // bf16 1.0
  const bf16x8 ones = {one_bf, one_bf, one_bf, one_bf,
                       one_bf, one_bf, one_bf, one_bf};

  f32x4 ACC[16];
#pragma unroll
  for (int ct = 0; ct < 16; ++ct) ACC[ct] = zero4;

  for (int h = 0; h < 8; ++h) {
    // S = q k^T (K=32, one k-step)
    f32x4 s[4];
#pragma unroll
    for (int ct = 0; ct < 4; ++ct) {
      const bf16x8 bk = *(const bf16x8*)&qk_lds[(ct * 16 + l15) * XSTR + h * 32 + lq * 8];
      s[ct] = mfma16(qf[h], bk, zero4);
    }
    // p = exp2(s*EXPSCALE + bias2)   (|s*scale+bias| << 88: no max needed)
#pragma unroll
    for (int ct = 0; ct < 4; ++ct)
#pragma unroll
      for (int r = 0; r < 4; ++r)
        s[ct][r] = __builtin_amdgcn_exp2f(s[ct][r] * EXPSCALE + bias_r[ct][r]);

    // P -> wave-local scratch (bf16)
#pragma unroll
    for (int ct = 0; ct < 4; ++ct)
#pragma unroll
      for (int r = 0; r < 4; ++r)
        sc[(lq * 4 + r) * SSTR + ct * 16 + l15] = f2bf(s[ct][r]);

    // PV (16x32, K=64) + row sums on the matrix pipe: osum = P @ ones
    f32x4 o[2], osum;
    o[0] = zero4; o[1] = zero4; osum = zero4;
#pragma unroll
    for (int kk = 0; kk < 2; ++kk) {
      const bf16x8 ap = *(const bf16x8*)&sc[l15 * SSTR + kk * 32 + lq * 8];
#pragma unroll
      for (int ct = 0; ct < 2; ++ct) {
        const bf16x8 bv = *(const bf16x8*)&vT_lds[(h * 32 + ct * 16 + l15) * VSTR + kk * 32 + lq * 8];
        o[ct] = mfma16(ap, bv, o[ct]);
      }
      osum = mfma16(ap, ones, osum);   // row sums, same C-frag rows as o
    }

    // normalize rows, stash oh (aliases p: p fully consumed)
    float rsum[4];
#pragma unroll
    for (int r = 0; r < 4; ++r) rsum[r] = 1.0f / osum[r];
#pragma unroll
    for (int ct = 0; ct < 2; ++ct)
#pragma unroll
      for (int r = 0; r < 4; ++r)
        sc[(lq * 4 + r) * SSTR + ct * 16 + l15] = f2bf(o[ct][r] * rsum[r]);

    // out-proj slice: ACC(16x256) += oh(16x32) @ w_out[h*32.., :]
    const bf16x8 ao = *(const bf16x8*)&sc[l15 * SSTR + lq * 8];
#pragma unroll
    for (int ct = 0; ct < 16; ++ct) {
      const bf16x8 bw = *(const bf16x8*)&woutT[((ct * 8 + h) * 4 + lq) * 128 + l15 * 8];
      ACC[ct] = mfma16(ao, bw, ACC[ct]);
    }
  }

  // ---------- phase 4: epilogue ----------
  {
#pragma unroll
    for (int ct = 0; ct < 16; ++ct) {
      const int n = ct * 16 + l15;
      const float bo = b_out[n];
#pragma unroll
      for (int r = 0; r < 4; ++r) {
        const int p = w * 16 + lq * 4 + r;
        const size_t off = img_base +
            (((size_t)(wy * 8 + (p >> 3)) * 128) + (wx * 8 + (p & 7))) * 256 + n;
        out[off] = ACC[ct][r] + bo;
      }
    }
  }
}

extern "C" void kernel_launch(void* const* d_in, const int* in_sizes, int n_in,
                              void* d_out, int out_size, void* d_ws, size_t ws_size,
                              hipStream_t stream) {
  const float* x       = (const float*)d_in[0];
  const float* w_qkv   = (const float*)d_in[1];
  const float* pos_emb = (const float*)d_in[2];
  const float* w_out   = (const float*)d_in[3];
  const float* b_out   = (const float*)d_in[4];
  float* out = (float*)d_out;

  unsigned short* wqkvT = (unsigned short*)d_ws;
  unsigned short* woutT = wqkvT + 768 * 256;
  float* bias64 = (float*)(woutT + 256 * 256);

  prep_kernel<<<96, 256, 0, stream>>>(w_qkv, w_out, pos_emb, wqkvT, woutT, bias64);
  winattn_kernel<<<2048, 256, 0, stream>>>(x, wqkvT, woutT, bias64, b_out, out);
}

// Round 5
// 135.008 us; speedup vs baseline: 5.8095x; 1.3623x over previous
//
#include <hip/hip_runtime.h>
#include <hip/hip_bf16.h>

// Fused Swin window attention for MI355X (gfx950) — round 5.
// One block per 8x8 window (2048 blocks x 256 threads, 4 waves), 2 blocks/CU.
// r4 was latency-chain bound (no pipe >16%, occupancy capped by LDS at 2/CU).
// r5 = ILP pass, same memory structure:
//   * QKV GEMM: software-pipelined k-steps (prefetch kk+1 A/B frags during
//     kk's MFMAs) — hides L2 weight-load latency.
//   * head loop: compute S(h+1)+exp between P(h) write and readback; hoist
//     all 16 woutT B-frags before PV — hides LDS round-trip + L2 latency.
//   * vT epilogue stores packed 4xbf16 -> b64 (64 scalar -> 16 vector writes).
//   * bias load moved after QKV GEMMs (less register liveness in phase 2).

typedef __attribute__((ext_vector_type(8))) short bf16x8;
typedef __attribute__((ext_vector_type(4))) float f32x4;

__device__ __forceinline__ f32x4 mfma16(bf16x8 a, bf16x8 b, f32x4 c) {
  return __builtin_amdgcn_mfma_f32_16x16x32_bf16(a, b, c, 0, 0, 0);
}

__device__ __forceinline__ unsigned short f2bf(float f) {
  __hip_bfloat16 h = __float2bfloat16(f);
  return *reinterpret_cast<unsigned short*>(&h);
}

#define LOG2E 1.4426950408889634f
#define EXPSCALE (0.17677669529663687f * 1.4426950408889634f)

// LDS layout (ushort elements)
#define XSTR 264     // x / q / k row stride (64 rows)
#define VSTR 72      // vT row stride (256 rows)
#define SSTR 72      // per-wave scratch row stride (16 rows)
#define OFF_A  0     // region A: x (64x264=16896) then vT (256x72=18432)
#define OFF_B  18432 // region B: q then k (64x264=16896)
#define OFF_SC 35328 // scratch: 4 waves x 16 x 72 = 4608
#define SMEM_ELTS 39936  // 79,872 bytes -> 2 blocks/CU

// Weight tiled layout: elem(n,k) -> ((((n>>4)*8+(k>>5))*4+((k>>3)&3))*16+(n&15))*8+(k&7)
__global__ void prep_kernel(const float* __restrict__ w_qkv,
                            const float* __restrict__ w_out,
                            const float* __restrict__ pos_emb,
                            unsigned short* __restrict__ wqkvT,
                            unsigned short* __restrict__ woutT,
                            float* __restrict__ bias64) {
  const int stride = gridDim.x * blockDim.x;
  const int tid = blockIdx.x * blockDim.x + threadIdx.x;
  for (int i = tid; i < 768 * 256; i += stride) {
    int n = i >> 8, k = i & 255;
    int off = ((((n >> 4) * 8 + (k >> 5)) * 4 + ((k >> 3) & 3)) * 16 + (n & 15)) * 8 + (k & 7);
    wqkvT[off] = f2bf(w_qkv[k * 768 + n]);
  }
  for (int i = tid; i < 256 * 256; i += stride) {
    int n = i >> 8, k = i & 255;
    int off = ((((n >> 4) * 8 + (k >> 5)) * 4 + ((k >> 3) & 3)) * 16 + (n & 15)) * 8 + (k & 7);
    woutT[off] = f2bf(w_out[k * 256 + n]);
  }
  for (int i = tid; i < 64 * 64; i += stride) {
    int a = i >> 6, b = i & 63;
    int d0 = (b >> 3) - (a >> 3) + 7;
    int d1 = (b & 7) - (a & 7) + 7;
    bias64[i] = pos_emb[d0 * 15 + d1] * LOG2E;   // pre-scaled for exp2
  }
}

// QKV GEMM, software-pipelined over k-steps: prefetch kk+1 while MFMAing kk.
#define QKV_MFMA(acc_, col0_)                                                    \
  {                                                                              \
    bf16x8 aP[4], bP[4], aN[4], bN[4];                                           \
    _Pragma("unroll")                                                            \
    for (int rt = 0; rt < 4; ++rt)                                               \
      aP[rt] = *(const bf16x8*)&x_lds[(rt * 16 + l15) * XSTR + lq * 8];          \
    _Pragma("unroll")                                                            \
    for (int ct = 0; ct < 4; ++ct)                                               \
      bP[ct] = *(const bf16x8*)&wqkvT[((((col0_) >> 4) + ct) * 32 + lq) * 128 + l15 * 8]; \
    _Pragma("unroll")                                                            \
    for (int kk = 0; kk < 8; ++kk) {                                             \
      if (kk < 7) {                                                              \
        const int ko = (kk + 1) * 32 + lq * 8;                                   \
        _Pragma("unroll")                                                        \
        for (int rt = 0; rt < 4; ++rt)                                           \
          aN[rt] = *(const bf16x8*)&x_lds[(rt * 16 + l15) * XSTR + ko];          \
        _Pragma("unroll")                                                        \
        for (int ct = 0; ct < 4; ++ct)                                           \
          bN[ct] = *(const bf16x8*)&wqkvT[(((((col0_) >> 4) + ct) * 8 + kk + 1) * 4 + lq) * 128 + l15 * 8]; \
      }                                                                          \
      _Pragma("unroll")                                                          \
      for (int rt = 0; rt < 4; ++rt)                                             \
        _Pragma("unroll")                                                        \
        for (int ct = 0; ct < 4; ++ct)                                           \
          acc_[rt][ct] = mfma16(aP[rt], bP[ct], acc_[rt][ct]);                   \
      _Pragma("unroll")                                                          \
      for (int rt = 0; rt < 4; ++rt) aP[rt] = aN[rt];                            \
      _Pragma("unroll")                                                          \
      for (int ct = 0; ct < 4; ++ct) bP[ct] = bN[ct];                            \
    }                                                                            \
  }

__global__ __launch_bounds__(256, 2)
void winattn_kernel(const float* __restrict__ x,
                    const unsigned short* __restrict__ wqkvT,
                    const unsigned short* __restrict__ woutT,
                    const float* __restrict__ bias64,
                    const float* __restrict__ b_out,
                    float* __restrict__ out) {
  __shared__ unsigned short smem[SMEM_ELTS];

  const int tid = threadIdx.x;
  const int lane = tid & 63;
  const int w = tid >> 6;
  const int l15 = lane & 15;
  const int lq = lane >> 4;

  const int bid = blockIdx.x;
  const int win = bid & 255;
  const int img = bid >> 8;
  const int wy = win >> 4, wx = win & 15;

  unsigned short* x_lds  = smem + OFF_A;   // x, later overwritten by vT
  unsigned short* vT_lds = smem + OFF_A;
  unsigned short* qk_lds = smem + OFF_B;   // q round-trip, then k
  unsigned short* sc = smem + OFF_SC + w * (16 * SSTR);

  const f32x4 zero4 = {0.f, 0.f, 0.f, 0.f};
  const size_t img_base = (size_t)img * 128 * 128 * 256;

  // ---------- phase 1: stage x window -> bf16 LDS (coalesced) ----------
  {
#pragma unroll
    for (int r = 0; r < 16; ++r) {
      int p = r * 4 + w;                 // pixel 0..63
      const float* src = x + img_base +
          (((size_t)(wy * 8 + (p >> 3)) * 128) + (wx * 8 + (p & 7))) * 256 + lane * 4;
      float4 v4 = *(const float4*)src;
      union { unsigned short u[4]; uint2 v; } pk;
      pk.u[0] = f2bf(v4.x); pk.u[1] = f2bf(v4.y);
      pk.u[2] = f2bf(v4.z); pk.u[3] = f2bf(v4.w);
      *(uint2*)&x_lds[p * XSTR + lane * 4] = pk.v;   // single b64 write
    }
  }
  __syncthreads();   // bar1

  // ---------- phase 2a: Q chunk (cols w*64..+64), round-trip via B ----------
  {
    f32x4 acc[4][4];
#pragma unroll
    for (int rt = 0; rt < 4; ++rt)
#pragma unroll
      for (int ct = 0; ct < 4; ++ct) acc[rt][ct] = zero4;
    QKV_MFMA(acc, w * 64)
#pragma unroll
    for (int rt = 0; rt < 4; ++rt)
#pragma unroll
      for (int ct = 0; ct < 4; ++ct)
#pragma unroll
        for (int r = 0; r < 4; ++r)
          qk_lds[(rt * 16 + lq * 4 + r) * XSTR + w * 64 + ct * 16 + l15] =
              f2bf(acc[rt][ct][r]);
  }
  __syncthreads();   // bar2

  // q A-frags for this wave's 16 rows
  bf16x8 qf[8];
#pragma unroll
  for (int h = 0; h < 8; ++h)
    qf[h] = *(const bf16x8*)&qk_lds[(w * 16 + l15) * XSTR + h * 32 + lq * 8];

  // ---------- phase 2b: K chunk (registers -> barrier -> LDS) ----------
  {
    f32x4 kacc[4][4];
#pragma unroll
    for (int rt = 0; rt < 4; ++rt)
#pragma unroll
      for (int ct = 0; ct < 4; ++ct) kacc[rt][ct] = zero4;
    QKV_MFMA(kacc, 256 + w * 64)
    __syncthreads();   // bar3: all qf reads done -> safe to overwrite B
#pragma unroll
    for (int rt = 0; rt < 4; ++rt)
#pragma unroll
      for (int ct = 0; ct < 4; ++ct)
#pragma unroll
        for (int r = 0; r < 4; ++r)
          qk_lds[(rt * 16 + lq * 4 + r) * XSTR + w * 64 + ct * 16 + l15] =
              f2bf(kacc[rt][ct][r]);
  }

  // ---------- phase 2c: V chunk (registers -> barrier -> LDS, transposed) ----------
  {
    f32x4 vacc[4][4];
#pragma unroll
    for (int rt = 0; rt < 4; ++rt)
#pragma unroll
      for (int ct = 0; ct < 4; ++ct) vacc[rt][ct] = zero4;
    QKV_MFMA(vacc, 512 + w * 64)
    __syncthreads();   // bar4: all x reads (region A) done -> safe to overwrite
    // vT rows = features, cols = pixels; per-lane r-values are contiguous -> b64
#pragma unroll
    for (int rt = 0; rt < 4; ++rt)
#pragma unroll
      for (int ct = 0; ct < 4; ++ct) {
        union { unsigned short u[4]; uint2 v; } pk;
#pragma unroll
        for (int r = 0; r < 4; ++r) pk.u[r] = f2bf(vacc[rt][ct][r]);
        *(uint2*)&vT_lds[(w * 64 + ct * 16 + l15) * VSTR + rt * 16 + lq * 4] = pk.v;
      }
  }
  __syncthreads();   // bar5

  // bias (pre-scaled by log2e), loaded late to keep phase-2 registers lean
  float bias_r[4][4];
#pragma unroll
  for (int ct = 0; ct < 4; ++ct)
#pragma unroll
    for (int r = 0; r < 4; ++r)
      bias_r[ct][r] = bias64[(w * 16 + lq * 4 + r) * 64 + ct * 16 + l15];

  // ---------- phase 3: attention + fused out-proj, head-pipelined ----------
  const short one_bf = (short)0x3F80;            // bf16 1.0
  const bf16x8 ones = {one_bf, one_bf, one_bf, one_bf,
                       one_bf, one_bf, one_bf, one_bf};

  f32x4 ACC[16];
#pragma unroll
  for (int ct = 0; ct < 16; ++ct) ACC[ct] = zero4;

  // prologue: S(0) -> exp -> s
  f32x4 s[4];
#pragma unroll
  for (int ct = 0; ct < 4; ++ct) {
    const bf16x8 bk = *(const bf16x8*)&qk_lds[(ct * 16 + l15) * XSTR + lq * 8];
    f32x4 t = mfma16(qf[0], bk, zero4);
#pragma unroll
    for (int r = 0; r < 4; ++r)
      s[ct][r] = __builtin_amdgcn_exp2f(t[r] * EXPSCALE + bias_r[ct][r]);
  }

#pragma unroll
  for (int h = 0; h < 8; ++h) {
    // 1. P(h) -> wave-local scratch
#pragma unroll
    for (int ct = 0; ct < 4; ++ct)
#pragma unroll
      for (int r = 0; r < 4; ++r)
        sc[(lq * 4 + r) * SSTR + ct * 16 + l15] = f2bf(s[ct][r]);

    // 2. S(h+1) + exp while the P write lands (hides LDS round-trip)
    f32x4 sn[4];
    if (h < 7) {
#pragma unroll
      for (int ct = 0; ct < 4; ++ct) {
        const bf16x8 bk = *(const bf16x8*)&qk_lds[(ct * 16 + l15) * XSTR + (h + 1) * 32 + lq * 8];
        f32x4 t = mfma16(qf[h + 1], bk, zero4);
#pragma unroll
        for (int r = 0; r < 4; ++r)
          sn[ct][r] = __builtin_amdgcn_exp2f(t[r] * EXPSCALE + bias_r[ct][r]);
      }
    }

    // 3. prefetch all 16 woutT B-frags for this head (L2 latency hidden)
    bf16x8 bw[16];
#pragma unroll
    for (int ct = 0; ct < 16; ++ct)
      bw[ct] = *(const bf16x8*)&woutT[((ct * 8 + h) * 4 + lq) * 128 + l15 * 8];

    // 4. PV (16x32, K=64) + row sums on the matrix pipe
    f32x4 o[2], osum;
    o[0] = zero4; o[1] = zero4; osum = zero4;
#pragma unroll
    for (int kk = 0; kk < 2; ++kk) {
      const bf16x8 ap = *(const bf16x8*)&sc[l15 * SSTR + kk * 32 + lq * 8];
#pragma unroll
      for (int ct = 0; ct < 2; ++ct) {
        const bf16x8 bv = *(const bf16x8*)&vT_lds[(h * 32 + ct * 16 + l15) * VSTR + kk * 32 + lq * 8];
        o[ct] = mfma16(ap, bv, o[ct]);
      }
      osum = mfma16(ap, ones, osum);
    }

    // 5. normalize rows, stash oh (aliases p: p fully consumed)
    float rsum[4];
#pragma unroll
    for (int r = 0; r < 4; ++r) rsum[r] = 1.0f / osum[r];
#pragma unroll
    for (int ct = 0; ct < 2; ++ct)
#pragma unroll
      for (int r = 0; r < 4; ++r)
        sc[(lq * 4 + r) * SSTR + ct * 16 + l15] = f2bf(o[ct][r] * rsum[r]);

    // 6. out-proj slice: ACC(16x256) += oh(16x32) @ w_out[h*32.., :]
    const bf16x8 ao = *(const bf16x8*)&sc[l15 * SSTR + lq * 8];
#pragma unroll
    for (int ct = 0; ct < 16; ++ct)
      ACC[ct] = mfma16(ao, bw[ct], ACC[ct]);

    // 7. shift pipeline
    if (h < 7) {
#pragma unroll
      for (int ct = 0; ct < 4; ++ct) s[ct] = sn[ct];
    }
  }

  // ---------- phase 4: epilogue ----------
  {
#pragma unroll
    for (int ct = 0; ct < 16; ++ct) {
      const int n = ct * 16 + l15;
      const float bo = b_out[n];
#pragma unroll
      for (int r = 0; r < 4; ++r) {
        const int p = w * 16 + lq * 4 + r;
        const size_t off = img_base +
            (((size_t)(wy * 8 + (p >> 3)) * 128) + (wx * 8 + (p & 7))) * 256 + n;
        out[off] = ACC[ct][r] + bo;
      }
    }
  }
}

extern "C" void kernel_launch(void* const* d_in, const int* in_sizes, int n_in,
                              void* d_out, int out_size, void* d_ws, size_t ws_size,
                              hipStream_t stream) {
  const float* x       = (const float*)d_in[0];
  const float* w_qkv   = (const float*)d_in[1];
  const float* pos_emb = (const float*)d_in[2];
  const float* w_out   = (const float*)d_in[3];
  const float* b_out   = (const float*)d_in[4];
  float* out = (float*)d_out;

  unsigned short* wqkvT = (unsigned short*)d_ws;
  unsigned short* woutT = wqkvT + 768 * 256;
  float* bias64 = (float*)(woutT + 256 * 256);

  prep_kernel<<<96, 256, 0, stream>>>(w_qkv, w_out, pos_emb, wqkvT, woutT, bias64);
  winattn_kernel<<<2048, 256, 0, stream>>>(x, wqkvT, woutT, bias64, b_out, out);
}